// Round 2
// baseline (7659.612 us; speedup 1.0000x reference)
//
#include <hip/hip_runtime.h>

typedef unsigned short u16;
typedef __attribute__((ext_vector_type(8))) __bf16 bf16x8;
typedef __attribute__((ext_vector_type(4))) float floatx4;
typedef __attribute__((ext_vector_type(4))) unsigned int uint4v;

#define NTOK 1296      // P + H*(NO+NA) = 16 + 32*40
#define BN_TOT 10368   // B * NTOK
#define DMODEL 768
#define DFF 3072
#define NHEAD 12
#define DHEAD 64
#define NLAYER 12
#define SCALE_QK 0.125f  // 1/sqrt(64)

__device__ __forceinline__ u16 f2bf(float f) {
    unsigned u = __builtin_bit_cast(unsigned, f);
    unsigned r = (u + 0x7FFFu + ((u >> 16) & 1u)) >> 16;
    return (u16)r;
}

__device__ __forceinline__ float gelu_f(float x) {
    float u = 0.7978845608028654f * (x + 0.044715f * x * x * x);
    float t = 1.f - 2.f / (__expf(2.f * u) + 1.f);   // tanh(u)
    return 0.5f * x * (1.f + t);
}

// mask rule: key j<16 (prefix) always visible; prefix rows see only prefix;
// obs(g=1) sees obs blocks tj<=ti; act(g=2) sees obs tj<=ti and act tj<=ti.
__device__ __forceinline__ bool rule_ok(int i, int j) {
    if (j < 16) return true;
    if (i < 16) return false;
    int qi = i - 16, qj = j - 16;
    int ti = qi / 40, tj = qj / 40;
    int gi = ((qi % 40) < 32) ? 1 : 2;
    int gj = ((qj % 40) < 32) ? 1 : 2;
    if (gj == 1) return tj <= ti;
    return (gi == 2) && (tj <= ti);
}

// ---------------- input assembly ----------------
__global__ void assemble_x(const float* __restrict__ prefix,
                           const float* __restrict__ obs,
                           const float* __restrict__ act,
                           float* __restrict__ X) {
    int idx = blockIdx.x * 256 + threadIdx.x;
    if (idx >= BN_TOT * DMODEL) return;
    int d = idx % DMODEL;
    int n = (idx / DMODEL) % NTOK;
    int b = idx / (DMODEL * NTOK);
    float v;
    if (n < 16) {
        v = prefix[((size_t)b * 16 + n) * DMODEL + d];
    } else {
        int q = n - 16;
        int m = q / 40, r = q % 40;
        if (r < 32) v = obs[(((size_t)b * 32 + m) * 32 + r) * DMODEL + d];
        else        v = act[(((size_t)b * 32 + m) * 8 + (r - 32)) * DMODEL + d];
    }
    X[idx] = v;
}

// masks are bool in the reference -> delivered as int32 by the harness
__global__ void build_pad(const int* __restrict__ pm,
                          const int* __restrict__ om,
                          const int* __restrict__ am,
                          unsigned char* __restrict__ pad) {
    int idx = blockIdx.x * 256 + threadIdx.x;
    if (idx >= BN_TOT) return;
    int n = idx % NTOK, b = idx / NTOK;
    int v;
    if (n < 16) v = pm[b * 16 + n];
    else {
        int q = n - 16;
        int m = q / 40, r = q % 40;
        v = (r < 32) ? om[(b * 32 + m) * 32 + r] : am[(b * 32 + m) * 8 + (r - 32)];
    }
    pad[idx] = (v != 0) ? 1 : 0;
}

// ---------------- weight transpose + cvt: W fp32 [K][Nc] -> bf16 [Nc][K] ----------------
__global__ void transpose_cvt(const float* __restrict__ src, u16* __restrict__ dst,
                              int K, int Nc, long layerStride) {
    src += (size_t)blockIdx.z * K * Nc;
    dst += (size_t)blockIdx.z * layerStride;
    __shared__ float tile[32][33];
    int n0 = blockIdx.x * 32, k0 = blockIdx.y * 32;
    int tx = threadIdx.x, ty = threadIdx.y;
#pragma unroll
    for (int i = 0; i < 4; ++i)
        tile[ty + i * 8][tx] = src[(size_t)(k0 + ty + i * 8) * Nc + n0 + tx];
    __syncthreads();
#pragma unroll
    for (int i = 0; i < 4; ++i) {
        int n = n0 + ty + i * 8;
        dst[(size_t)n * K + k0 + tx] = f2bf(tile[tx][ty + i * 8]);
    }
}

// ---------------- LayerNorm: fp32 x -> bf16 (or fp32 for final) ----------------
__global__ __launch_bounds__(256) void ln_kernel(const float* __restrict__ x,
                                                 const float* __restrict__ s,
                                                 const float* __restrict__ bb,
                                                 u16* __restrict__ obf,
                                                 float* __restrict__ of32) {
    int row = blockIdx.x;
    const float* xr = x + (size_t)row * DMODEL;
    int t = threadIdx.x;
    float v0 = xr[t], v1 = xr[t + 256], v2 = xr[t + 512];
    float sum = v0 + v1 + v2;
    float sq = v0 * v0 + v1 * v1 + v2 * v2;
#pragma unroll
    for (int d = 32; d > 0; d >>= 1) {
        sum += __shfl_down(sum, d);
        sq  += __shfl_down(sq, d);
    }
    __shared__ float ps[8], pq[8];
    int w = t >> 6, lane = t & 63;
    if (lane == 0) { ps[w] = sum; pq[w] = sq; }
    __syncthreads();
    if (t == 0) {
        float S = ps[0] + ps[1] + ps[2] + ps[3];
        float Q = pq[0] + pq[1] + pq[2] + pq[3];
        float mu = S * (1.f / DMODEL);
        float var = Q * (1.f / DMODEL) - mu * mu;
        ps[4] = mu; pq[4] = rsqrtf(var + 1e-6f);
    }
    __syncthreads();
    float mu = ps[4], rs = pq[4];
#pragma unroll
    for (int i = 0; i < 3; ++i) {
        int col = t + i * 256;
        float v = (i == 0 ? v0 : (i == 1 ? v1 : v2));
        float y = (v - mu) * rs * s[col] + bb[col];
        if (obf) obf[(size_t)row * DMODEL + col] = f2bf(y);
        else     of32[(size_t)row * DMODEL + col] = y;
    }
}

// ---------------- GEMM: C = A(bf16 MxK) @ Wt(bf16 [Nc][K])^T + bias, epilogues ----------------
// EPI 0: bf16 out in [b][nh][n][dh] head layout (Q/K)
// EPI 1: bf16 out in [b][nh][dh][n] transposed head layout (V^T)
// EPI 2: gelu -> bf16 out [M][Nc]
// EPI 3: fp32 out[M][Nc] = resid + acc + bias
template <int EPI>
__global__ __launch_bounds__(256) void gemm_k(const u16* __restrict__ A,
                                              const u16* __restrict__ Bt,
                                              const float* __restrict__ bias,
                                              const float* __restrict__ resid,
                                              void* __restrict__ outp,
                                              int M, int Nc, int K) {
    __shared__ __attribute__((aligned(16))) u16 As[128 * 40];
    __shared__ __attribute__((aligned(16))) u16 Bs[128 * 40];
    int tid = threadIdx.x;
    int bc = blockIdx.x, br = blockIdx.y;
    int lane = tid & 63, w = tid >> 6;
    int wr = (w >> 1) * 64, wc = (w & 1) * 64;
    int lr = lane & 15, lk = (lane >> 4) * 8;
    floatx4 acc[4][4] = {};
    int prow = tid >> 2, pch = (tid & 3) * 8;
    const u16* Ab = A + (size_t)(br * 128 + prow) * K + pch;
    const u16* Bb = Bt + (size_t)(bc * 128 + prow) * K + pch;

    for (int k0 = 0; k0 < K; k0 += 32) {
        __syncthreads();
        uint4v va0 = *(const uint4v*)(Ab + k0);
        uint4v va1 = *(const uint4v*)(Ab + (size_t)64 * K + k0);
        uint4v vb0 = *(const uint4v*)(Bb + k0);
        uint4v vb1 = *(const uint4v*)(Bb + (size_t)64 * K + k0);
        *(uint4v*)&As[prow * 40 + pch] = va0;
        *(uint4v*)&As[(prow + 64) * 40 + pch] = va1;
        *(uint4v*)&Bs[prow * 40 + pch] = vb0;
        *(uint4v*)&Bs[(prow + 64) * 40 + pch] = vb1;
        __syncthreads();
        bf16x8 af[4], bf[4];
#pragma unroll
        for (int i = 0; i < 4; ++i) af[i] = *(const bf16x8*)&As[(wr + i * 16 + lr) * 40 + lk];
#pragma unroll
        for (int i = 0; i < 4; ++i) bf[i] = *(const bf16x8*)&Bs[(wc + i * 16 + lr) * 40 + lk];
#pragma unroll
        for (int i = 0; i < 4; ++i)
#pragma unroll
            for (int j = 0; j < 4; ++j)
                acc[i][j] = __builtin_amdgcn_mfma_f32_16x16x32_bf16(af[i], bf[j], acc[i][j], 0, 0, 0);
    }

    int gr0 = br * 128 + wr, gc0 = bc * 128 + wc;
#pragma unroll
    for (int i = 0; i < 4; ++i) {
#pragma unroll
        for (int j = 0; j < 4; ++j) {
#pragma unroll
            for (int r = 0; r < 4; ++r) {
                int grow = gr0 + i * 16 + (lane >> 4) * 4 + r;
                int gcol = gc0 + j * 16 + lr;
                float v = acc[i][j][r] + bias[gcol];
                if constexpr (EPI == 0) {
                    int b = grow / NTOK, n = grow % NTOK;
                    int nh = gcol >> 6, dh = gcol & 63;
                    ((u16*)outp)[(((size_t)b * NHEAD + nh) * NTOK + n) * DHEAD + dh] = f2bf(v);
                } else if constexpr (EPI == 1) {
                    int b = grow / NTOK, n = grow % NTOK;
                    int nh = gcol >> 6, dh = gcol & 63;
                    ((u16*)outp)[(((size_t)b * NHEAD + nh) * DHEAD + dh) * NTOK + n] = f2bf(v);
                } else if constexpr (EPI == 2) {
                    ((u16*)outp)[(size_t)grow * Nc + gcol] = f2bf(gelu_f(v));
                } else {
                    size_t idx = (size_t)grow * Nc + gcol;
                    ((float*)outp)[idx] = resid[idx] + v;
                }
            }
        }
    }
}

// ---------------- fused attention (flash-style, per (b,h,64 q-rows)) ----------------
__global__ __launch_bounds__(256) void attn_k(const u16* __restrict__ Q,
                                              const u16* __restrict__ Kb,
                                              const u16* __restrict__ Vt,
                                              const unsigned char* __restrict__ pad,
                                              u16* __restrict__ O) {
    __shared__ __attribute__((aligned(16))) u16 plds[4][16 * 72];
    int qt = blockIdx.x, h = blockIdx.y, b = blockIdx.z;
    int tid = threadIdx.x, lane = tid & 63, w = tid >> 6;
    int rg = lane >> 4, lc = lane & 15;
    int q0 = qt * 64 + w * 16;
    size_t bh = (size_t)(b * NHEAD + h);

    const u16* qb = Q + (bh * NTOK + min(q0 + lc, NTOK - 1)) * DHEAD;
    bf16x8 qf0 = *(const bf16x8*)(qb + rg * 8);
    bf16x8 qf1 = *(const bf16x8*)(qb + 32 + rg * 8);

    floatx4 oacc[4] = {};
    float mi[4] = {-3.0e38f, -3.0e38f, -3.0e38f, -3.0e38f};
    float li[4] = {0.f, 0.f, 0.f, 0.f};
    const unsigned char* padb = pad + (size_t)b * NTOK;

    for (int j0 = 0; j0 < 1344; j0 += 64) {
        floatx4 s[4];
#pragma unroll
        for (int ct = 0; ct < 4; ++ct) {
            int key = j0 + ct * 16 + lc;
            int keyc = min(key, NTOK - 1);
            const u16* kb = Kb + (bh * NTOK + keyc) * DHEAD;
            bf16x8 kf0 = *(const bf16x8*)(kb + rg * 8);
            bf16x8 kf1 = *(const bf16x8*)(kb + 32 + rg * 8);
            floatx4 sa = {};
            sa = __builtin_amdgcn_mfma_f32_16x16x32_bf16(qf0, kf0, sa, 0, 0, 0);
            sa = __builtin_amdgcn_mfma_f32_16x16x32_bf16(qf1, kf1, sa, 0, 0, 0);
            s[ct] = sa;
        }
#pragma unroll
        for (int ct = 0; ct < 4; ++ct) {
            int col = j0 + ct * 16 + lc;
            bool colok = (col < NTOK) && (padb[min(col, NTOK - 1)] != 0);
#pragma unroll
            for (int r = 0; r < 4; ++r) {
                int row = q0 + rg * 4 + r;
                bool ok = colok && (row < NTOK) && rule_ok(row, col);
                s[ct][r] = ok ? s[ct][r] * SCALE_QK : -1.0e9f;
            }
        }
#pragma unroll
        for (int r = 0; r < 4; ++r) {
            float mx = fmaxf(fmaxf(s[0][r], s[1][r]), fmaxf(s[2][r], s[3][r]));
            mx = fmaxf(mx, __shfl_xor(mx, 1));
            mx = fmaxf(mx, __shfl_xor(mx, 2));
            mx = fmaxf(mx, __shfl_xor(mx, 4));
            mx = fmaxf(mx, __shfl_xor(mx, 8));
            float mnew = fmaxf(mi[r], mx);
            float alpha = __expf(mi[r] - mnew);
            float rs = 0.f;
#pragma unroll
            for (int ct = 0; ct < 4; ++ct) {
                float p = __expf(s[ct][r] - mnew);
                s[ct][r] = p;
                rs += p;
            }
            rs += __shfl_xor(rs, 1);
            rs += __shfl_xor(rs, 2);
            rs += __shfl_xor(rs, 4);
            rs += __shfl_xor(rs, 8);
            li[r] = li[r] * alpha + rs;
            mi[r] = mnew;
#pragma unroll
            for (int ct = 0; ct < 4; ++ct) oacc[ct][r] *= alpha;
        }
#pragma unroll
        for (int ct = 0; ct < 4; ++ct)
#pragma unroll
            for (int r = 0; r < 4; ++r)
                plds[w][(rg * 4 + r) * 72 + ct * 16 + lc] = f2bf(s[ct][r]);
        __syncthreads();
        bf16x8 pf0 = *(const bf16x8*)&plds[w][lc * 72 + rg * 8];
        bf16x8 pf1 = *(const bf16x8*)&plds[w][lc * 72 + 32 + rg * 8];
#pragma unroll
        for (int ct = 0; ct < 4; ++ct) {
            const u16* vb = Vt + (bh * DHEAD + ct * 16 + lc) * NTOK + j0;
            bf16x8 vf0 = *(const bf16x8*)(vb + rg * 8);
            bf16x8 vf1 = *(const bf16x8*)(vb + 32 + rg * 8);
            oacc[ct] = __builtin_amdgcn_mfma_f32_16x16x32_bf16(pf0, vf0, oacc[ct], 0, 0, 0);
            oacc[ct] = __builtin_amdgcn_mfma_f32_16x16x32_bf16(pf1, vf1, oacc[ct], 0, 0, 0);
        }
        __syncthreads();
    }
#pragma unroll
    for (int r = 0; r < 4; ++r) {
        int row = q0 + rg * 4 + r;
        if (row < NTOK) {
            float inv = 1.f / li[r];
#pragma unroll
            for (int ct = 0; ct < 4; ++ct)
                O[((size_t)b * NTOK + row) * DMODEL + h * DHEAD + ct * 16 + lc] = f2bf(oacc[ct][r] * inv);
        }
    }
}

// ---------------- launcher ----------------
extern "C" void kernel_launch(void* const* d_in, const int* in_sizes, int n_in,
                              void* d_out, int out_size, void* d_ws, size_t ws_size,
                              hipStream_t stream) {
    const float* prefix = (const float*)d_in[0];
    const float* obs    = (const float*)d_in[1];
    const float* act    = (const float*)d_in[2];
    const float* ln1_s  = (const float*)d_in[3];
    const float* ln1_b  = (const float*)d_in[4];
    const float* ln2_s  = (const float*)d_in[5];
    const float* ln2_b  = (const float*)d_in[6];
    const float* wq = (const float*)d_in[7];
    const float* wk = (const float*)d_in[8];
    const float* wv = (const float*)d_in[9];
    const float* wo = (const float*)d_in[10];
    const float* bq = (const float*)d_in[11];
    const float* bk = (const float*)d_in[12];
    const float* bv = (const float*)d_in[13];
    const float* bo = (const float*)d_in[14];
    const float* w1 = (const float*)d_in[15];
    const float* b1 = (const float*)d_in[16];
    const float* w2 = (const float*)d_in[17];
    const float* b2 = (const float*)d_in[18];
    const float* lnf_s = (const float*)d_in[19];
    const float* lnf_b = (const float*)d_in[20];
    const int* pm = (const int*)d_in[21];
    const int* om = (const int*)d_in[22];
    const int* am = (const int*)d_in[23];
    float* out = (float*)d_out;

    char* ws = (char*)d_ws;
    size_t off = 0;
    auto carve = [&](size_t bytes) -> char* {
        char* p = ws + off;
        off += (bytes + 255) & ~(size_t)255;
        return p;
    };
    float* X   = (float*)carve((size_t)BN_TOT * DMODEL * 4);
    u16*   Hb  = (u16*)carve((size_t)BN_TOT * DMODEL * 2);
    u16*   Qb  = (u16*)carve((size_t)BN_TOT * DMODEL * 2);
    u16*   Kbf = (u16*)carve((size_t)BN_TOT * DMODEL * 2);
    u16*   Vt  = (u16*)carve((size_t)BN_TOT * DMODEL * 2 + 256);  // +pad for tail frag reads
    u16*   Ob  = (u16*)carve((size_t)BN_TOT * DMODEL * 2);
    u16*   MID = (u16*)carve((size_t)BN_TOT * DFF * 2);
    unsigned char* PAD = (unsigned char*)carve(BN_TOT);
    u16*   WT  = (u16*)carve((size_t)NLAYER * 7077888 * 2);
    if (off > ws_size) return;  // workspace too small -> fail loudly in validation

    const long LSTR = 7077888;  // per-layer elems in WT
    const long OWQ = 0, OWK = 589824, OWV = 1179648, OWO = 1769472, OW1 = 2359296, OW2 = 4718592;

    dim3 blk(256);
    assemble_x<<<(BN_TOT * DMODEL + 255) / 256, blk, 0, stream>>>(prefix, obs, act, X);
    build_pad<<<(BN_TOT + 255) / 256, blk, 0, stream>>>(pm, om, am, PAD);

    dim3 tb(32, 8);
    transpose_cvt<<<dim3(DMODEL / 32, DMODEL / 32, NLAYER), tb, 0, stream>>>(wq, WT + OWQ, DMODEL, DMODEL, LSTR);
    transpose_cvt<<<dim3(DMODEL / 32, DMODEL / 32, NLAYER), tb, 0, stream>>>(wk, WT + OWK, DMODEL, DMODEL, LSTR);
    transpose_cvt<<<dim3(DMODEL / 32, DMODEL / 32, NLAYER), tb, 0, stream>>>(wv, WT + OWV, DMODEL, DMODEL, LSTR);
    transpose_cvt<<<dim3(DMODEL / 32, DMODEL / 32, NLAYER), tb, 0, stream>>>(wo, WT + OWO, DMODEL, DMODEL, LSTR);
    transpose_cvt<<<dim3(DFF / 32, DMODEL / 32, NLAYER), tb, 0, stream>>>(w1, WT + OW1, DMODEL, DFF, LSTR);
    transpose_cvt<<<dim3(DMODEL / 32, DFF / 32, NLAYER), tb, 0, stream>>>(w2, WT + OW2, DFF, DMODEL, LSTR);

    dim3 g6(DMODEL / 128, BN_TOT / 128);
    dim3 g24(DFF / 128, BN_TOT / 128);
    dim3 ga(21, NHEAD, 8);

    for (int l = 0; l < NLAYER; ++l) {
        const u16* WTl = WT + (size_t)l * LSTR;
        ln_kernel<<<BN_TOT, blk, 0, stream>>>(X, ln1_s + l * DMODEL, ln1_b + l * DMODEL, Hb, nullptr);
        gemm_k<0><<<g6, blk, 0, stream>>>(Hb, WTl + OWQ, bq + l * DMODEL, nullptr, Qb, BN_TOT, DMODEL, DMODEL);
        gemm_k<0><<<g6, blk, 0, stream>>>(Hb, WTl + OWK, bk + l * DMODEL, nullptr, Kbf, BN_TOT, DMODEL, DMODEL);
        gemm_k<1><<<g6, blk, 0, stream>>>(Hb, WTl + OWV, bv + l * DMODEL, nullptr, Vt, BN_TOT, DMODEL, DMODEL);
        attn_k<<<ga, blk, 0, stream>>>(Qb, Kbf, Vt, PAD, Ob);
        gemm_k<3><<<g6, blk, 0, stream>>>(Ob, WTl + OWO, bo + l * DMODEL, X, X, BN_TOT, DMODEL, DMODEL);
        ln_kernel<<<BN_TOT, blk, 0, stream>>>(X, ln2_s + l * DMODEL, ln2_b + l * DMODEL, Hb, nullptr);
        gemm_k<2><<<g24, blk, 0, stream>>>(Hb, WTl + OW1, b1 + l * DFF, nullptr, MID, BN_TOT, DFF, DMODEL);
        gemm_k<3><<<g6, blk, 0, stream>>>(MID, WTl + OW2, b2 + l * DMODEL, X, X, BN_TOT, DMODEL, DFF);
    }
    ln_kernel<<<BN_TOT, blk, 0, stream>>>(X, lnf_s, lnf_b, nullptr, out);
}

// Round 3
// 6947.401 us; speedup vs baseline: 1.1025x; 1.1025x over previous
//
#include <hip/hip_runtime.h>

typedef unsigned short u16;
typedef __attribute__((ext_vector_type(8))) __bf16 bf16x8;
typedef __attribute__((ext_vector_type(4))) float floatx4;

#define NTOK 1296      // P + H*(NO+NA) = 16 + 32*40
#define BN_TOT 10368   // B * NTOK
#define DMODEL 768
#define DFF 3072
#define NHEAD 12
#define DHEAD 64
#define NLAYER 12
#define SCALE_QK 0.125f  // 1/sqrt(64)

__device__ __forceinline__ u16 f2bf(float f) {
    unsigned u = __builtin_bit_cast(unsigned, f);
    unsigned r = (u + 0x7FFFu + ((u >> 16) & 1u)) >> 16;
    return (u16)r;
}

__device__ __forceinline__ float gelu_f(float x) {
    float u = 0.7978845608028654f * (x + 0.044715f * x * x * x);
    float t = 1.f - 2.f / (__expf(2.f * u) + 1.f);   // tanh(u)
    return 0.5f * x * (1.f + t);
}

__device__ __forceinline__ bool rule_ok(int i, int j) {
    if (j < 16) return true;
    if (i < 16) return false;
    int qi = i - 16, qj = j - 16;
    int ti = qi / 40, tj = qj / 40;
    int gi = ((qi % 40) < 32) ? 1 : 2;
    int gj = ((qj % 40) < 32) ? 1 : 2;
    if (gj == 1) return tj <= ti;
    return (gi == 2) && (tj <= ti);
}

// ---------------- input assembly ----------------
__global__ void assemble_x(const float* __restrict__ prefix,
                           const float* __restrict__ obs,
                           const float* __restrict__ act,
                           float* __restrict__ X) {
    int idx = blockIdx.x * 256 + threadIdx.x;
    if (idx >= BN_TOT * DMODEL) return;
    int d = idx % DMODEL;
    int n = (idx / DMODEL) % NTOK;
    int b = idx / (DMODEL * NTOK);
    float v;
    if (n < 16) {
        v = prefix[((size_t)b * 16 + n) * DMODEL + d];
    } else {
        int q = n - 16;
        int m = q / 40, r = q % 40;
        if (r < 32) v = obs[(((size_t)b * 32 + m) * 32 + r) * DMODEL + d];
        else        v = act[(((size_t)b * 32 + m) * 8 + (r - 32)) * DMODEL + d];
    }
    X[idx] = v;
}

__global__ void build_pad(const int* __restrict__ pm,
                          const int* __restrict__ om,
                          const int* __restrict__ am,
                          unsigned char* __restrict__ pad) {
    int idx = blockIdx.x * 256 + threadIdx.x;
    if (idx >= BN_TOT) return;
    int n = idx % NTOK, b = idx / NTOK;
    int v;
    if (n < 16) v = pm[b * 16 + n];
    else {
        int q = n - 16;
        int m = q / 40, r = q % 40;
        v = (r < 32) ? om[(b * 32 + m) * 32 + r] : am[(b * 32 + m) * 8 + (r - 32)];
    }
    pad[idx] = (v != 0) ? 1 : 0;
}

// ---------------- weight transpose + cvt: W fp32 [K][Nc] -> bf16 [Nc][K] ----------------
__global__ void transpose_cvt(const float* __restrict__ src, u16* __restrict__ dst,
                              int K, int Nc, long layerStride) {
    src += (size_t)blockIdx.z * K * Nc;
    dst += (size_t)blockIdx.z * layerStride;
    __shared__ float tile[32][33];
    int n0 = blockIdx.x * 32, k0 = blockIdx.y * 32;
    int tx = threadIdx.x, ty = threadIdx.y;
#pragma unroll
    for (int i = 0; i < 4; ++i)
        tile[ty + i * 8][tx] = src[(size_t)(k0 + ty + i * 8) * Nc + n0 + tx];
    __syncthreads();
#pragma unroll
    for (int i = 0; i < 4; ++i) {
        int n = n0 + ty + i * 8;
        dst[(size_t)n * K + k0 + tx] = f2bf(tile[tx][ty + i * 8]);
    }
}

// ---------------- LayerNorm ----------------
__global__ __launch_bounds__(256) void ln_kernel(const float* __restrict__ x,
                                                 const float* __restrict__ s,
                                                 const float* __restrict__ bb,
                                                 u16* __restrict__ obf,
                                                 float* __restrict__ of32) {
    int row = blockIdx.x;
    const float* xr = x + (size_t)row * DMODEL;
    int t = threadIdx.x;
    float v0 = xr[t], v1 = xr[t + 256], v2 = xr[t + 512];
    float sum = v0 + v1 + v2;
    float sq = v0 * v0 + v1 * v1 + v2 * v2;
#pragma unroll
    for (int d = 32; d > 0; d >>= 1) {
        sum += __shfl_down(sum, d);
        sq  += __shfl_down(sq, d);
    }
    __shared__ float ps[8], pq[8];
    int w = t >> 6, lane = t & 63;
    if (lane == 0) { ps[w] = sum; pq[w] = sq; }
    __syncthreads();
    if (t == 0) {
        float S = ps[0] + ps[1] + ps[2] + ps[3];
        float Q = pq[0] + pq[1] + pq[2] + pq[3];
        float mu = S * (1.f / DMODEL);
        float var = Q * (1.f / DMODEL) - mu * mu;
        ps[4] = mu; pq[4] = rsqrtf(var + 1e-6f);
    }
    __syncthreads();
    float mu = ps[4], rs = pq[4];
#pragma unroll
    for (int i = 0; i < 3; ++i) {
        int col = t + i * 256;
        float v = (i == 0 ? v0 : (i == 1 ? v1 : v2));
        float y = (v - mu) * rs * s[col] + bb[col];
        if (obf) obf[(size_t)row * DMODEL + col] = f2bf(y);
        else     of32[(size_t)row * DMODEL + col] = y;
    }
}

// ---------------- GEMM with global_load_lds staging + XOR-swizzled LDS ----------------
template <int EPI>
__global__ __launch_bounds__(256) void gemm_k(const u16* __restrict__ A,
                                              const u16* __restrict__ Bt,
                                              const float* __restrict__ bias,
                                              const float* __restrict__ resid,
                                              void* __restrict__ outp,
                                              int M, int Nc, int K) {
    __shared__ __attribute__((aligned(16))) u16 As[4096];  // 512 slots x 16B
    __shared__ __attribute__((aligned(16))) u16 Bs[4096];
    int tid = threadIdx.x;
    int bc = blockIdx.x, br = blockIdx.y;
    int lane = tid & 63, w = tid >> 6;
    int wr = (w >> 1) * 64, wc = (w & 1) * 64;
    int lr = lane & 15, C = lane >> 4;
    floatx4 acc[4][4] = {};

    int r0 = tid >> 2;       // staging row within 64-row half (0..63)
    int cph = tid & 3;       // physical 16B chunk slot within row
    const u16* Abase = A + (size_t)(br * 128) * K;
    const u16* Bbase = Bt + (size_t)(bc * 128) * K;

    for (int k0 = 0; k0 < K; k0 += 32) {
        __syncthreads();
#pragma unroll
        for (int i = 0; i < 2; ++i) {
            int r = i * 64 + r0;
            int cl = cph ^ ((r >> 1) & 3);
            const u16* ga = Abase + (size_t)r * K + k0 + cl * 8;
            const u16* gb = Bbase + (size_t)r * K + k0 + cl * 8;
            __builtin_amdgcn_global_load_lds(
                (const __attribute__((address_space(1))) void*)ga,
                (__attribute__((address_space(3))) void*)&As[(i * 256 + w * 64) * 8], 16, 0, 0);
            __builtin_amdgcn_global_load_lds(
                (const __attribute__((address_space(1))) void*)gb,
                (__attribute__((address_space(3))) void*)&Bs[(i * 256 + w * 64) * 8], 16, 0, 0);
        }
        __syncthreads();
        bf16x8 af[4], bf[4];
#pragma unroll
        for (int i = 0; i < 4; ++i) {
            int R = wr + i * 16 + lr;
            af[i] = *(const bf16x8*)&As[(R * 4 + (C ^ ((R >> 1) & 3))) * 8];
        }
#pragma unroll
        for (int i = 0; i < 4; ++i) {
            int R = wc + i * 16 + lr;
            bf[i] = *(const bf16x8*)&Bs[(R * 4 + (C ^ ((R >> 1) & 3))) * 8];
        }
#pragma unroll
        for (int i = 0; i < 4; ++i)
#pragma unroll
            for (int j = 0; j < 4; ++j)
                acc[i][j] = __builtin_amdgcn_mfma_f32_16x16x32_bf16(af[i], bf[j], acc[i][j], 0, 0, 0);
    }

    int gr0 = br * 128 + wr, gc0 = bc * 128 + wc;
#pragma unroll
    for (int i = 0; i < 4; ++i) {
#pragma unroll
        for (int j = 0; j < 4; ++j) {
#pragma unroll
            for (int r = 0; r < 4; ++r) {
                int grow = gr0 + i * 16 + (lane >> 4) * 4 + r;
                int gcol = gc0 + j * 16 + lr;
                float v = acc[i][j][r] + bias[gcol];
                if constexpr (EPI == 0) {
                    int b = grow / NTOK, n = grow % NTOK;
                    int nh = gcol >> 6, dh = gcol & 63;
                    ((u16*)outp)[(((size_t)b * NHEAD + nh) * NTOK + n) * DHEAD + dh] = f2bf(v);
                } else if constexpr (EPI == 1) {
                    int b = grow / NTOK, n = grow % NTOK;
                    int nh = gcol >> 6, dh = gcol & 63;
                    ((u16*)outp)[(((size_t)b * NHEAD + nh) * DHEAD + dh) * NTOK + n] = f2bf(v);
                } else if constexpr (EPI == 2) {
                    ((u16*)outp)[(size_t)grow * Nc + gcol] = f2bf(gelu_f(v));
                } else {
                    size_t idx = (size_t)grow * Nc + gcol;
                    ((float*)outp)[idx] = resid[idx] + v;
                }
            }
        }
    }
}

// ---------------- fused attention with causal key-tile skip ----------------
__global__ __launch_bounds__(256) void attn_k(const u16* __restrict__ Q,
                                              const u16* __restrict__ Kb,
                                              const u16* __restrict__ Vt,
                                              const unsigned char* __restrict__ pad,
                                              u16* __restrict__ O) {
    __shared__ __attribute__((aligned(16))) u16 plds[4][16 * 72];
    int qt = blockIdx.x, h = blockIdx.y, b = blockIdx.z;
    int tid = threadIdx.x, lane = tid & 63, w = tid >> 6;
    int rg = lane >> 4, lc = lane & 15;
    int q0 = qt * 64 + w * 16;
    size_t bh = (size_t)(b * NHEAD + h);

    int lastrow = min(qt * 64 + 63, NTOK - 1);
    int jend = (lastrow < 16) ? 16 : 16 + 40 * ((lastrow - 16) / 40 + 1);
    jend = min(jend, NTOK);
    int njt = (jend + 63) >> 6;

    const u16* qb = Q + (bh * NTOK + min(q0 + lc, NTOK - 1)) * DHEAD;
    bf16x8 qf0 = *(const bf16x8*)(qb + rg * 8);
    bf16x8 qf1 = *(const bf16x8*)(qb + 32 + rg * 8);

    floatx4 oacc[4] = {};
    float mi[4] = {-3.0e38f, -3.0e38f, -3.0e38f, -3.0e38f};
    float li[4] = {0.f, 0.f, 0.f, 0.f};
    const unsigned char* padb = pad + (size_t)b * NTOK;

    for (int jt = 0; jt < njt; ++jt) {
        int j0 = jt * 64;
        floatx4 s[4];
#pragma unroll
        for (int ct = 0; ct < 4; ++ct) {
            int key = j0 + ct * 16 + lc;
            int keyc = min(key, NTOK - 1);
            const u16* kb = Kb + (bh * NTOK + keyc) * DHEAD;
            bf16x8 kf0 = *(const bf16x8*)(kb + rg * 8);
            bf16x8 kf1 = *(const bf16x8*)(kb + 32 + rg * 8);
            floatx4 sa = {};
            sa = __builtin_amdgcn_mfma_f32_16x16x32_bf16(qf0, kf0, sa, 0, 0, 0);
            sa = __builtin_amdgcn_mfma_f32_16x16x32_bf16(qf1, kf1, sa, 0, 0, 0);
            s[ct] = sa;
        }
#pragma unroll
        for (int ct = 0; ct < 4; ++ct) {
            int col = j0 + ct * 16 + lc;
            bool colok = (col < NTOK) && (padb[min(col, NTOK - 1)] != 0);
#pragma unroll
            for (int r = 0; r < 4; ++r) {
                int row = q0 + rg * 4 + r;
                bool ok = colok && (row < NTOK) && rule_ok(row, col);
                s[ct][r] = ok ? s[ct][r] * SCALE_QK : -1.0e9f;
            }
        }
#pragma unroll
        for (int r = 0; r < 4; ++r) {
            float mx = fmaxf(fmaxf(s[0][r], s[1][r]), fmaxf(s[2][r], s[3][r]));
            mx = fmaxf(mx, __shfl_xor(mx, 1));
            mx = fmaxf(mx, __shfl_xor(mx, 2));
            mx = fmaxf(mx, __shfl_xor(mx, 4));
            mx = fmaxf(mx, __shfl_xor(mx, 8));
            float mnew = fmaxf(mi[r], mx);
            float alpha = __expf(mi[r] - mnew);
            float rs = 0.f;
#pragma unroll
            for (int ct = 0; ct < 4; ++ct) {
                float p = __expf(s[ct][r] - mnew);
                s[ct][r] = p;
                rs += p;
            }
            rs += __shfl_xor(rs, 1);
            rs += __shfl_xor(rs, 2);
            rs += __shfl_xor(rs, 4);
            rs += __shfl_xor(rs, 8);
            li[r] = li[r] * alpha + rs;
            mi[r] = mnew;
#pragma unroll
            for (int ct = 0; ct < 4; ++ct) oacc[ct][r] *= alpha;
        }
#pragma unroll
        for (int ct = 0; ct < 4; ++ct)
#pragma unroll
            for (int r = 0; r < 4; ++r)
                plds[w][(rg * 4 + r) * 72 + ct * 16 + lc] = f2bf(s[ct][r]);
        __syncthreads();
        bf16x8 pf0 = *(const bf16x8*)&plds[w][lc * 72 + rg * 8];
        bf16x8 pf1 = *(const bf16x8*)&plds[w][lc * 72 + 32 + rg * 8];
#pragma unroll
        for (int ct = 0; ct < 4; ++ct) {
            const u16* vb = Vt + (bh * DHEAD + ct * 16 + lc) * NTOK + j0;
            bf16x8 vf0 = *(const bf16x8*)(vb + rg * 8);
            bf16x8 vf1 = *(const bf16x8*)(vb + 32 + rg * 8);
            oacc[ct] = __builtin_amdgcn_mfma_f32_16x16x32_bf16(pf0, vf0, oacc[ct], 0, 0, 0);
            oacc[ct] = __builtin_amdgcn_mfma_f32_16x16x32_bf16(pf1, vf1, oacc[ct], 0, 0, 0);
        }
        __syncthreads();
    }
#pragma unroll
    for (int r = 0; r < 4; ++r) {
        int row = q0 + rg * 4 + r;
        if (row < NTOK) {
            float inv = 1.f / li[r];
#pragma unroll
            for (int ct = 0; ct < 4; ++ct)
                O[((size_t)b * NTOK + row) * DMODEL + h * DHEAD + ct * 16 + lc] = f2bf(oacc[ct][r] * inv);
        }
    }
}

// ---------------- launcher ----------------
extern "C" void kernel_launch(void* const* d_in, const int* in_sizes, int n_in,
                              void* d_out, int out_size, void* d_ws, size_t ws_size,
                              hipStream_t stream) {
    const float* prefix = (const float*)d_in[0];
    const float* obs    = (const float*)d_in[1];
    const float* act    = (const float*)d_in[2];
    const float* ln1_s  = (const float*)d_in[3];
    const float* ln1_b  = (const float*)d_in[4];
    const float* ln2_s  = (const float*)d_in[5];
    const float* ln2_b  = (const float*)d_in[6];
    const float* wq = (const float*)d_in[7];
    const float* wk = (const float*)d_in[8];
    const float* wv = (const float*)d_in[9];
    const float* wo = (const float*)d_in[10];
    const float* bq = (const float*)d_in[11];
    const float* bk = (const float*)d_in[12];
    const float* bv = (const float*)d_in[13];
    const float* bo = (const float*)d_in[14];
    const float* w1 = (const float*)d_in[15];
    const float* b1 = (const float*)d_in[16];
    const float* w2 = (const float*)d_in[17];
    const float* b2 = (const float*)d_in[18];
    const float* lnf_s = (const float*)d_in[19];
    const float* lnf_b = (const float*)d_in[20];
    const int* pm = (const int*)d_in[21];
    const int* om = (const int*)d_in[22];
    const int* am = (const int*)d_in[23];
    float* out = (float*)d_out;

    char* ws = (char*)d_ws;
    size_t off = 0;
    auto carve = [&](size_t bytes) -> char* {
        char* p = ws + off;
        off += (bytes + 255) & ~(size_t)255;
        return p;
    };
    float* X   = (float*)carve((size_t)BN_TOT * DMODEL * 4);
    u16*   Hb  = (u16*)carve((size_t)BN_TOT * DMODEL * 2);
    u16*   Qb  = (u16*)carve((size_t)BN_TOT * DMODEL * 2);
    u16*   Kbf = (u16*)carve((size_t)BN_TOT * DMODEL * 2);
    u16*   Vt  = (u16*)carve((size_t)BN_TOT * DMODEL * 2 + 256);
    u16*   Ob  = (u16*)carve((size_t)BN_TOT * DMODEL * 2);
    u16*   MID = (u16*)carve((size_t)BN_TOT * DFF * 2);
    unsigned char* PAD = (unsigned char*)carve(BN_TOT);
    u16*   WT  = (u16*)carve((size_t)NLAYER * 7077888 * 2);
    if (off > ws_size) return;

    const long LSTR = 7077888;
    const long OWQ = 0, OWK = 589824, OWV = 1179648, OWO = 1769472, OW1 = 2359296, OW2 = 4718592;

    dim3 blk(256);
    assemble_x<<<(BN_TOT * DMODEL + 255) / 256, blk, 0, stream>>>(prefix, obs, act, X);
    build_pad<<<(BN_TOT + 255) / 256, blk, 0, stream>>>(pm, om, am, PAD);

    dim3 tb(32, 8);
    transpose_cvt<<<dim3(DMODEL / 32, DMODEL / 32, NLAYER), tb, 0, stream>>>(wq, WT + OWQ, DMODEL, DMODEL, LSTR);
    transpose_cvt<<<dim3(DMODEL / 32, DMODEL / 32, NLAYER), tb, 0, stream>>>(wk, WT + OWK, DMODEL, DMODEL, LSTR);
    transpose_cvt<<<dim3(DMODEL / 32, DMODEL / 32, NLAYER), tb, 0, stream>>>(wv, WT + OWV, DMODEL, DMODEL, LSTR);
    transpose_cvt<<<dim3(DMODEL / 32, DMODEL / 32, NLAYER), tb, 0, stream>>>(wo, WT + OWO, DMODEL, DMODEL, LSTR);
    transpose_cvt<<<dim3(DFF / 32, DMODEL / 32, NLAYER), tb, 0, stream>>>(w1, WT + OW1, DMODEL, DFF, LSTR);
    transpose_cvt<<<dim3(DMODEL / 32, DFF / 32, NLAYER), tb, 0, stream>>>(w2, WT + OW2, DFF, DMODEL, LSTR);

    dim3 g6(DMODEL / 128, BN_TOT / 128);
    dim3 g24(DFF / 128, BN_TOT / 128);
    dim3 ga(21, NHEAD, 8);

    for (int l = 0; l < NLAYER; ++l) {
        const u16* WTl = WT + (size_t)l * LSTR;
        ln_kernel<<<BN_TOT, blk, 0, stream>>>(X, ln1_s + l * DMODEL, ln1_b + l * DMODEL, Hb, nullptr);
        gemm_k<0><<<g6, blk, 0, stream>>>(Hb, WTl + OWQ, bq + l * DMODEL, nullptr, Qb, BN_TOT, DMODEL, DMODEL);
        gemm_k<0><<<g6, blk, 0, stream>>>(Hb, WTl + OWK, bk + l * DMODEL, nullptr, Kbf, BN_TOT, DMODEL, DMODEL);
        gemm_k<1><<<g6, blk, 0, stream>>>(Hb, WTl + OWV, bv + l * DMODEL, nullptr, Vt, BN_TOT, DMODEL, DMODEL);
        attn_k<<<ga, blk, 0, stream>>>(Qb, Kbf, Vt, PAD, Ob);
        gemm_k<3><<<g6, blk, 0, stream>>>(Ob, WTl + OWO, bo + l * DMODEL, X, X, BN_TOT, DMODEL, DMODEL);
        ln_kernel<<<BN_TOT, blk, 0, stream>>>(X, ln2_s + l * DMODEL, ln2_b + l * DMODEL, Hb, nullptr);
        gemm_k<2><<<g24, blk, 0, stream>>>(Hb, WTl + OW1, b1 + l * DFF, nullptr, MID, BN_TOT, DFF, DMODEL);
        gemm_k<3><<<g6, blk, 0, stream>>>(MID, WTl + OW2, b2 + l * DMODEL, X, X, BN_TOT, DMODEL, DFF);
    }
    ln_kernel<<<BN_TOT, blk, 0, stream>>>(X, lnf_s, lnf_b, nullptr, out);
}